// Round 1
// baseline (306.472 us; speedup 1.0000x reference)
//
#include <hip/hip_runtime.h>
#include <hip/hip_bf16.h>

typedef __bf16 bf16_t;
typedef __bf16 bf16x8 __attribute__((ext_vector_type(8)));
typedef float f32x4 __attribute__((ext_vector_type(4)));

#define NB 32
#define CIN 128
#define HIN 64
#define WIN 64
#define OCH 256
#define OHW 62

// ---------------------------------------------------------------------------
// Pre-kernel 1: weights fp32 [256][128][3][3] -> bf16 wt[tap][o][c]
// ---------------------------------------------------------------------------
__global__ __launch_bounds__(256) void conv_wt_kernel(const float* __restrict__ w,
                                                      bf16_t* __restrict__ wt) {
  int e = blockIdx.x * 256 + threadIdx.x;      // 256*128*9 = 294912 exactly
  int o = e / 1152;
  int r = e - o * 1152;
  int c = r / 9;
  int t = r - c * 9;
  wt[(t * 256 + o) * 128 + c] = (bf16_t)w[e];
}

// ---------------------------------------------------------------------------
// Pre-kernel 2: x fp32 NCHW -> bf16 NHWC  xt[b][h][w][c]
// one block per (h, b, ctile64): transpose 64c x 64w via LDS
// ---------------------------------------------------------------------------
__global__ __launch_bounds__(256) void conv_xt_kernel(const float* __restrict__ x,
                                                      bf16_t* __restrict__ xt) {
  __shared__ float tile[64][65];               // +1 pad: conflict-free both phases
  const int h = blockIdx.x, b = blockIdx.y, c0 = blockIdx.z * 64;
  const int tid = threadIdx.x;
  const int wcol = tid & 63;
  const int cr = tid >> 6;                     // 0..3
  const float* src = x + (((size_t)b * CIN + c0) * HIN + h) * WIN;
#pragma unroll
  for (int rr = 0; rr < 16; ++rr) {
    int c = rr * 4 + cr;
    tile[c][wcol] = src[(size_t)c * (HIN * WIN) + wcol];  // coalesced over w
  }
  __syncthreads();
  const int w = tid >> 2;                      // 0..63
  const int cg = (tid & 3) * 16;               // 0,16,32,48
  bf16x8 v0, v1;
#pragma unroll
  for (int k = 0; k < 8; ++k) v0[k] = (bf16_t)tile[cg + k][w];
#pragma unroll
  for (int k = 0; k < 8; ++k) v1[k] = (bf16_t)tile[cg + 8 + k][w];
  bf16_t* dst = xt + (((size_t)b * HIN + h) * WIN + w) * CIN + c0 + cg;
  *(bf16x8*)(dst) = v0;                        // 2x16B contiguous, coalesced
  *(bf16x8*)(dst + 8) = v1;
}

// ---------------------------------------------------------------------------
// Main: implicit GEMM. Block = (b, i0=2*bx): out tile 256 o x (2 rows x 64 j).
// 8 waves = 4M x 2N, wave tile 64o x 64p. K = (c-chunk 64) x 9 taps x (2 ksub).
// LDS: xs [4h*64w rows][128B c] swizzled; wsm [256 o rows][128B c] swizzled.
// Swizzle: byte_off ^= (row&7)<<4, applied on the GLOBAL source (linear LDS
// dest for global_load_lds) and on every ds_read address.
// ---------------------------------------------------------------------------
__device__ __forceinline__ void async16(const void* gsrc, void* ldst) {
  __builtin_amdgcn_global_load_lds((const __attribute__((address_space(1))) void*)gsrc,
                                   (__attribute__((address_space(3))) void*)ldst, 16, 0, 0);
}

__global__ __launch_bounds__(512) void conv_main_kernel(const bf16_t* __restrict__ xt,
                                                        const bf16_t* __restrict__ wt,
                                                        float* __restrict__ out) {
  __shared__ __align__(16) char smem[65536];
  char* xs = smem;                 // 32 KB
  char* wsm = smem + 32768;        // 32 KB (OOB xs reads for masked j land here: harmless)

  const int tid = threadIdx.x;
  const int lane = tid & 63;
  const int wid = tid >> 6;
  const int l16 = lane & 15;
  const int lhi = lane >> 4;
  const int wm = wid >> 1, wn = wid & 1;
  const int o_base = wm * 64;
  const int b = blockIdx.y;
  const int i0 = blockIdx.x * 2;

  const char* xt_b = (const char*)xt;
  const char* wt_b = (const char*)wt;

  f32x4 acc[4][4];
#pragma unroll
  for (int m = 0; m < 4; ++m)
#pragma unroll
    for (int n = 0; n < 4; ++n) acc[m][n] = (f32x4){0.f, 0.f, 0.f, 0.f};

  const int swzA = (l16 & 7) << 4;

  for (int c0 = 0; c0 < 128; c0 += 64) {
    // ---- stage x slab: rows i0..i0+3, w 0..63, c0..c0+63 ----
    {
      const char* base = xt_b + ((((size_t)b * HIN + i0) * WIN) * CIN + c0) * 2;
#pragma unroll
      for (int it = 0; it < 4; ++it) {
        int slot = it * 512 + tid;           // 2048 slots of 16B
        int row = slot >> 3;                 // hloc*64 + w
        int off = (slot & 7) * 16;
        int srcoff = off ^ ((row & 7) << 4); // pre-swizzled source
        async16(base + (size_t)row * 256 + srcoff, xs + slot * 16);
      }
    }
    for (int kh = 0; kh < 3; ++kh) {
      for (int kw = 0; kw < 3; ++kw) {
        // ---- stage W tile: wt[tap][0..255][c0..c0+63] ----
        {
          const char* base = wt_b + ((size_t)((kh * 3 + kw) * 256) * 128 + c0) * 2;
#pragma unroll
          for (int it = 0; it < 4; ++it) {
            int slot = it * 512 + tid;
            int row = slot >> 3;
            int off = (slot & 7) * 16;
            int srcoff = off ^ ((row & 7) << 4);
            async16(base + (size_t)row * 256 + srcoff, wsm + slot * 16);
          }
        }
        __syncthreads();   // drains vmcnt: x slab + W tile both ready

        const int swzB = ((l16 + kw) & 7) << 4;
        const int srow0 = (wn + kh) * 64 + l16 + kw;
#pragma unroll
        for (int ks = 0; ks < 2; ++ks) {
          const int cb = ks * 64 + lhi * 16;
          bf16x8 a[4], bb[4];
#pragma unroll
          for (int m = 0; m < 4; ++m) {
            int addr = (o_base + m * 16 + l16) * 128 + (cb ^ swzA);
            a[m] = *(const bf16x8*)(wsm + addr);
          }
#pragma unroll
          for (int n = 0; n < 4; ++n) {
            int addr = (srow0 + n * 16) * 128 + (cb ^ swzB);
            bb[n] = *(const bf16x8*)(xs + addr);
          }
#pragma unroll
          for (int m = 0; m < 4; ++m)
#pragma unroll
            for (int n = 0; n < 4; ++n)
              acc[m][n] = __builtin_amdgcn_mfma_f32_16x16x32_bf16(a[m], bb[n], acc[m][n], 0, 0, 0);
        }
        __syncthreads();   // protect W tile (and x slab at c0 rollover)
      }
    }
  }

  // ---- epilogue: C/D layout col=lane&15 (j), row=(lane>>4)*4+reg (o) ----
  const int oi = i0 + wn;
#pragma unroll
  for (int n = 0; n < 4; ++n) {
    int j = n * 16 + l16;
    if (j < 62) {
#pragma unroll
      for (int m = 0; m < 4; ++m) {
        int o = o_base + m * 16 + lhi * 4;
        float* op = out + ((size_t)(b * 256 + o) * OHW + oi) * OHW + j;
#pragma unroll
        for (int r = 0; r < 4; ++r) op[(size_t)r * (OHW * OHW)] = acc[m][n][r];
      }
    }
  }
}

// ---------------------------------------------------------------------------
extern "C" void kernel_launch(void* const* d_in, const int* in_sizes, int n_in,
                              void* d_out, int out_size, void* d_ws, size_t ws_size,
                              hipStream_t stream) {
  const float* x = (const float*)d_in[0];
  const float* w = (const float*)d_in[1];
  float* out = (float*)d_out;

  bf16_t* xt = (bf16_t*)d_ws;                                        // 33,554,432 B
  bf16_t* wt = (bf16_t*)((char*)d_ws + (size_t)NB * HIN * WIN * CIN * 2);  // +589,824 B

  conv_wt_kernel<<<dim3(294912 / 256), dim3(256), 0, stream>>>(w, wt);
  conv_xt_kernel<<<dim3(HIN, NB, 2), dim3(256), 0, stream>>>(x, xt);
  conv_main_kernel<<<dim3(31, NB), dim3(512), 0, stream>>>(xt, wt, out);
}